// Round 10
// baseline (75.192 us; speedup 1.0000x reference)
//
#include <hip/hip_runtime.h>
#include <cstdint>
#include <cmath>

#define NN   4096
#define DXX  128
#define DD   64
#define KK   256
#define HH   256
#define DIN  192   // DD + DXX
#define ROWS 16
#define NT   512
#define GRID (NN/ROWS)   // 256 blocks, 1 per CU (8 waves -> 2 waves/SIMD)

// readlane: broadcast lane l's value to an SGPR (uniform), feeding v_fma's scalar slot
#define RL(v,l) __int_as_float(__builtin_amdgcn_readlane(__float_as_int(v),(l)))

// ---------------- Threefry-2x32 (20 rounds), exact JAX semantics ----------------
__device__ __forceinline__ uint32_t rotl32(uint32_t v, uint32_t r){ return (v<<r)|(v>>(32u-r)); }

__device__ __forceinline__ void tf2x32(uint32_t k0, uint32_t k1,
                                       uint32_t x0, uint32_t x1,
                                       uint32_t& o0, uint32_t& o1){
  const uint32_t ks0=k0, ks1=k1, ks2 = k0 ^ k1 ^ 0x1BD11BDAu;
  x0 += ks0; x1 += ks1;
  x0+=x1; x1=rotl32(x1,13); x1^=x0;
  x0+=x1; x1=rotl32(x1,15); x1^=x0;
  x0+=x1; x1=rotl32(x1,26); x1^=x0;
  x0+=x1; x1=rotl32(x1, 6); x1^=x0;
  x0+=ks1; x1+=ks2+1u;
  x0+=x1; x1=rotl32(x1,17); x1^=x0;
  x0+=x1; x1=rotl32(x1,29); x1^=x0;
  x0+=x1; x1=rotl32(x1,16); x1^=x0;
  x0+=x1; x1=rotl32(x1,24); x1^=x0;
  x0+=ks2; x1+=ks0+2u;
  x0+=x1; x1=rotl32(x1,13); x1^=x0;
  x0+=x1; x1=rotl32(x1,15); x1^=x0;
  x0+=x1; x1=rotl32(x1,26); x1^=x0;
  x0+=x1; x1=rotl32(x1, 6); x1^=x0;
  x0+=ks0; x1+=ks1+3u;
  x0+=x1; x1=rotl32(x1,17); x1^=x0;
  x0+=x1; x1=rotl32(x1,29); x1^=x0;
  x0+=x1; x1=rotl32(x1,16); x1^=x0;
  x0+=x1; x1=rotl32(x1,24); x1^=x0;
  x0+=ks1; x1+=ks2+4u;
  x0+=x1; x1=rotl32(x1,13); x1^=x0;
  x0+=x1; x1=rotl32(x1,15); x1^=x0;
  x0+=x1; x1=rotl32(x1,26); x1^=x0;
  x0+=x1; x1=rotl32(x1, 6); x1^=x0;
  x0+=ks2; x1+=ks0+5u;
  o0=x0; o1=x1;
}

__device__ __forceinline__ float gumbel_of(uint32_t ka0, uint32_t ka1, uint32_t idx){
  uint32_t o0,o1; tf2x32(ka0,ka1,0u,idx,o0,o1);
  const uint32_t bits = o0 ^ o1;
  const float TINY = 1.17549435e-38f;
  const float f = __uint_as_float((bits>>9) | 0x3F800000u) - 1.0f;
  const float u = fmaxf(TINY, f + TINY);
  return -logf(-logf(u));
}

// LDS layout (bytes):
//  [0,12288)      in_s[16][192]            } overlaid after MLP2 by stg[64][65] (16640 B)
//  [12288,28672)  h1  [16][256]            }
//  [28672,45056)  h2  [16][256]
//  [45056,49152)  sgt [16][64]
//  [49152,81920)  sp[2][16][256] (distance partials)
#define OFF_H1   12288
#define OFF_H2   28672
#define OFF_SGT  45056
#define OFF_SP   49152

__global__ __launch_bounds__(NT,2) void k_fused(
    const float* __restrict__ z, const float* __restrict__ ks,
    const float* __restrict__ xt, const void* __restrict__ maskp,
    const float* __restrict__ tr, const float* __restrict__ spk,
    const float* __restrict__ W1, const float* __restrict__ b1,
    const float* __restrict__ W2, const float* __restrict__ b2,
    const float* __restrict__ W3, const float* __restrict__ b3,
    const float* __restrict__ Cg, const int* __restrict__ seedp,
    float* __restrict__ out_z, float* __restrict__ out_kl,
    float* __restrict__ out_dkl, float* __restrict__ out_qk)
{
  const int t    = threadIdx.x;
  const int lane = t & 63;
  const int wv   = t >> 6;          // wave 0..7
  const int col  = t & 255;         // distance-phase column
  const int rh   = t >> 8;          // distance-phase d-half
  const int rg   = wv >> 2;         // MLP1/2 row group (0/1) -> rows rg*8..rg*8+7
  const int cg   = wv & 3;          // MLP1/2 col group -> cols cg*64..cg*64+63
  const int r0   = rg * 8;
  const int colx = cg*64 + lane;
  const int n0   = blockIdx.x * ROWS;
  const int nA   = n0 + wv;         // finalize: wave wv owns rows nA and nB
  const int nB   = n0 + 8 + wv;

  __shared__ __align__(16) char smem[81920];
  float (*in_s)[DIN] = (float(*)[DIN]) smem;
  float (*h1 )[HH]   = (float(*)[HH]) (smem + OFF_H1);
  float (*h2 )[HH]   = (float(*)[HH]) (smem + OFF_H2);
  float (*sgt)[DD]   = (float(*)[DD]) (smem + OFF_SGT);
  float *sp          = (float*)       (smem + OFF_SP);
  float (*stg)[65]   = (float(*)[65]) smem;              // codebook chunk overlay
  __shared__ int sh_flag;

  // ---- early long-latency loads: ks rows -> kidx -> transition rows; mask raw ----
  auto kidx_of=[&](const float4& kq)->int{
    int kv=0x7fffffff;
    if (isfinite(kq.x)&&kq.x>0.5f) kv=4*lane+0;
    if (isfinite(kq.y)&&kq.y>0.5f&&4*lane+1<kv) kv=4*lane+1;
    if (isfinite(kq.z)&&kq.z>0.5f&&4*lane+2<kv) kv=4*lane+2;
    if (isfinite(kq.w)&&kq.w>0.5f&&4*lane+3<kv) kv=4*lane+3;
    unsigned long long bl=__ballot(kv!=0x7fffffff);
    if (bl){ int src=(int)__builtin_ctzll(bl); kv=__shfl(kv,src,64); } else kv=0;
    return kv;
  };
  const float4 ksA = ((const float4*)ks)[(size_t)nA*(KK/4)+lane];
  const float4 ksB = ((const float4*)ks)[(size_t)nB*(KK/4)+lane];
  const int kA = kidx_of(ksA), kB = kidx_of(ksB);
  const float4 trA = ((const float4*)tr)[(size_t)nA*(KK*KK/4)+(size_t)kA*(KK/4)+lane];
  const float4 trB = ((const float4*)tr)[(size_t)nB*(KK*KK/4)+(size_t)kB*(KK/4)+lane];
  const unsigned char mbA = ((const unsigned char*)maskp)[nA];
  const unsigned char mbB = ((const unsigned char*)maskp)[nB];
  const uint32_t      mwA = ((const uint32_t*)maskp)[nA];
  const uint32_t      mwB = ((const uint32_t*)maskp)[nB];

  // ---- mask dtype autodetect ----
  if (t==0) sh_flag = 0;
  __syncthreads();
  {
    const uint32_t* mw = (const uint32_t*)maskp;
    uint32_t bad=0;
    #pragma unroll
    for (int q=0;q<2;++q){ uint32_t wd=mw[t+q*NT]; if (wd!=0u && wd!=1u && wd!=0x3F800000u) bad=1; }
    if (bad) atomicOr(&sh_flag,1);
  }

  // ---- MLP input staging ----
  for (int i=t; i<ROWS*DIN; i+=NT){
    int r=i/DIN, d=i%DIN; int n=n0+r; float v;
    if (d<DD){ v = z[(size_t)n*DD+d]; if(!isfinite(v)) v=0.f; }
    else     { v = xt[(size_t)n*DXX + (d-DD)]; }
    in_s[r][d] = v;
  }
  __syncthreads();
  const int flag = sh_flag;

  // ============ MLP1: tanh([z,x]@W1+b1) — lane-resident acts + readlane ============
  {
    float4 A[8];
    #pragma unroll
    for (int r=0;r<8;++r) A[r] = *(const float4*)&in_s[r0+r][4*lane];  // lanes 48+ unused garbage
    float acc[8];
    const float bb = b1[colx];
    #pragma unroll
    for (int r=0;r<8;++r) acc[r]=bb;
    const float* wp = W1 + colx;
    float w0=wp[0], w1=wp[HH], w2=wp[2*HH], w3=wp[3*HH];
    #pragma unroll 1
    for (int l=0; l<48; ++l){
      float nw0=0,nw1=0,nw2=0,nw3=0;
      if (l<47){ const float* q=wp+(size_t)(4*l+4)*HH; nw0=q[0]; nw1=q[HH]; nw2=q[2*HH]; nw3=q[3*HH]; }
      #pragma unroll
      for (int r=0;r<8;++r) acc[r]+=RL(A[r].x,l)*w0;
      #pragma unroll
      for (int r=0;r<8;++r) acc[r]+=RL(A[r].y,l)*w1;
      #pragma unroll
      for (int r=0;r<8;++r) acc[r]+=RL(A[r].z,l)*w2;
      #pragma unroll
      for (int r=0;r<8;++r) acc[r]+=RL(A[r].w,l)*w3;
      w0=nw0; w1=nw1; w2=nw2; w3=nw3;
    }
    #pragma unroll
    for (int r=0;r<8;++r) h1[r0+r][colx] = tanhf(acc[r]);
  }
  __syncthreads();

  // ============ MLP2: tanh(h1@W2+b2) ============
  {
    float4 A[8];
    #pragma unroll
    for (int r=0;r<8;++r) A[r] = *(const float4*)&h1[r0+r][4*lane];
    float acc[8];
    const float bb = b2[colx];
    #pragma unroll
    for (int r=0;r<8;++r) acc[r]=bb;
    const float* wp = W2 + colx;
    float w0=wp[0], w1=wp[HH], w2=wp[2*HH], w3=wp[3*HH];
    #pragma unroll 1
    for (int l=0; l<64; ++l){
      float nw0=0,nw1=0,nw2=0,nw3=0;
      if (l<63){ const float* q=wp+(size_t)(4*l+4)*HH; nw0=q[0]; nw1=q[HH]; nw2=q[2*HH]; nw3=q[3*HH]; }
      #pragma unroll
      for (int r=0;r<8;++r) acc[r]+=RL(A[r].x,l)*w0;
      #pragma unroll
      for (int r=0;r<8;++r) acc[r]+=RL(A[r].y,l)*w1;
      #pragma unroll
      for (int r=0;r<8;++r) acc[r]+=RL(A[r].z,l)*w2;
      #pragma unroll
      for (int r=0;r<8;++r) acc[r]+=RL(A[r].w,l)*w3;
      w0=nw0; w1=nw1; w2=nw2; w3=nw3;
    }
    #pragma unroll
    for (int r=0;r<8;++r) h2[r0+r][colx] = tanhf(acc[r]);
  }
  __syncthreads();

  // ============ MLP3: gt = h2@W3+b3 (2 rows/wave, lane=col) ============
  {
    const int rr = wv*2;
    float4 A0 = *(const float4*)&h2[rr+0][4*lane];
    float4 A1 = *(const float4*)&h2[rr+1][4*lane];
    float a0 = b3[lane], a1 = b3[lane];
    const float* wp = W3 + lane;
    float w0=wp[0], w1=wp[DD], w2=wp[2*DD], w3=wp[3*DD];
    #pragma unroll 1
    for (int l=0; l<64; ++l){
      float nw0=0,nw1=0,nw2=0,nw3=0;
      if (l<63){ const float* q=wp+(size_t)(4*l+4)*DD; nw0=q[0]; nw1=q[DD]; nw2=q[2*DD]; nw3=q[3*DD]; }
      a0+=RL(A0.x,l)*w0; a1+=RL(A1.x,l)*w0;
      a0+=RL(A0.y,l)*w1; a1+=RL(A1.y,l)*w1;
      a0+=RL(A0.z,l)*w2; a1+=RL(A1.z,l)*w2;
      a0+=RL(A0.w,l)*w3; a1+=RL(A1.w,l)*w3;
      w0=nw0; w1=nw1; w2=nw2; w3=nw3;
    }
    sgt[rr+0][lane]=a0; sgt[rr+1][lane]=a1;
  }

  // ---- gumbel precompute (pure VALU; mask known) ----
  uint32_t ka0,ka1;
  tf2x32(0u,(uint32_t)seedp[0],0u,0u,ka0,ka1);   // partitionable split: k_rng
  const bool mA = flag ? (mbA!=0) : (mwA!=0u);
  const bool mB = flag ? (mbB!=0) : (mwB!=0u);
  float gA0=0,gA1=0,gA2=0,gA3=0,gB0=0,gB1=0,gB2=0,gB3=0;
  if (!mA){
    gA0=gumbel_of(ka0,ka1,(uint32_t)(nA*KK+4*lane+0));
    gA1=gumbel_of(ka0,ka1,(uint32_t)(nA*KK+4*lane+1));
    gA2=gumbel_of(ka0,ka1,(uint32_t)(nA*KK+4*lane+2));
    gA3=gumbel_of(ka0,ka1,(uint32_t)(nA*KK+4*lane+3));
  }
  if (!mB){
    gB0=gumbel_of(ka0,ka1,(uint32_t)(nB*KK+4*lane+0));
    gB1=gumbel_of(ka0,ka1,(uint32_t)(nB*KK+4*lane+1));
    gB2=gumbel_of(ka0,ka1,(uint32_t)(nB*KK+4*lane+2));
    gB3=gumbel_of(ka0,ka1,(uint32_t)(nB*KK+4*lane+3));
  }

  // ---- codebook -> registers: thread (col,rh) holds C[col][rh*32..+31] ----
  float creg[32];
  #pragma unroll 1
  for (int cc=0; cc<4; ++cc){
    __syncthreads();                 // protect stg region reuse (sgt published on cc=0)
    #pragma unroll
    for (int q=0;q<2;++q){
      int f=q*NT+t;
      float4 v=((const float4*)Cg)[cc*1024+f];
      int cl=f>>4, d0=(f&15)*4;
      stg[cl][d0+0]=v.x; stg[cl][d0+1]=v.y; stg[cl][d0+2]=v.z; stg[cl][d0+3]=v.w;
    }
    __syncthreads();
    if ((col>>6)==cc){
      #pragma unroll
      for (int j=0;j<32;++j) creg[j]=stg[col&63][rh*32+j];
    }
  }
  __syncthreads();

  // ---- distance partials (half-split) into sp ----
  #pragma unroll 1
  for (int r=0;r<ROWS;++r){
    float p=0.f;
    #pragma unroll
    for (int d4=0; d4<32; d4+=4){
      float4 s4 = *(const float4*)&sgt[r][rh*32+d4];
      float df;
      df=s4.x-creg[d4+0]; p+=df*df;
      df=s4.y-creg[d4+1]; p+=df*df;
      df=s4.z-creg[d4+2]; p+=df*df;
      df=s4.w-creg[d4+3]; p+=df*df;
    }
    sp[rh*4096 + r*256 + col] = p;
  }
  __syncthreads();

  // ---- wave-local finalize: wave wv owns rows nA (r=wv) and nB (r=wv+8) ----
  auto process=[&](int n,int r,const float4& ksq,const float4& trq,bool m,
                   float g0,float g1,float g2,float g3){
    // VQ argmin (first-index tie-break)
    float4 p0 = *(const float4*)&sp[       r*256 + 4*lane];
    float4 p1 = *(const float4*)&sp[4096 + r*256 + 4*lane];
    float dv = sqrtf(p0.x+p1.x); int di = 4*lane;
    { float d1=sqrtf(p0.y+p1.y); if(d1<dv){dv=d1;di=4*lane+1;}
      float d2=sqrtf(p0.z+p1.z); if(d2<dv){dv=d2;di=4*lane+2;}
      float d3=sqrtf(p0.w+p1.w); if(d3<dv){dv=d3;di=4*lane+3;} }
    #pragma unroll
    for (int mm=32;mm;mm>>=1){
      float ov=__shfl_xor(dv,mm,64); int oi=__shfl_xor(di,mm,64);
      if (ov<dv||(ov==dv&&oi<di)){dv=ov;di=oi;}
    }
    const int qk=di;

    // prior normalization
    float s=((trq.x+trq.y)+trq.z)+trq.w;
    #pragma unroll
    for (int mm=32;mm;mm>>=1) s+=__shfl_xor(s,mm,64);
    float q0=trq.x/s, q1=trq.y/s, q2=trq.z/s, q3=trq.w/s;
    { bool f0=isfinite(ksq.x),f1=isfinite(ksq.y),f2=isfinite(ksq.z),f3=isfinite(ksq.w);
      if (__any(!(f0&&f1&&f2&&f3))){
        float4 sq=((const float4*)spk)[(size_t)n*(KK/4)+lane];
        if(!f0)q0=sq.x; if(!f1)q1=sq.y; if(!f2)q2=sq.z; if(!f3)q3=sq.w;
      } }
    const float lp0=logf(q0), lp1=logf(q1), lp2=logf(q2), lp3=logf(q3);
    const int jq=qk&3;
    float lps=(jq==0)?lp0:((jq==1)?lp1:((jq==2)?lp2:lp3));
    const float logqk=__shfl(lps,qk>>2,64);

    int sel;
    if (m){ sel=qk; }
    else {
      float sc=g0+lp0; int si=4*lane;
      { float g=g1+lp1; if(g>sc){sc=g;si=4*lane+1;} }
      { float g=g2+lp2; if(g>sc){sc=g;si=4*lane+2;} }
      { float g=g3+lp3; if(g>sc){sc=g;si=4*lane+3;} }
      #pragma unroll
      for (int mm=32;mm;mm>>=1){
        float ov=__shfl_xor(sc,mm,64); int oi=__shfl_xor(si,mm,64);
        if (ov>sc||(ov==sc&&oi<si)){sc=ov;si=oi;}
      }
      sel=si;
    }

    ((float4*)out_qk)[(size_t)n*(KK/4)+lane]=make_float4(
      (4*lane+0==qk)?1.f:0.f,(4*lane+1==qk)?1.f:0.f,
      (4*lane+2==qk)?1.f:0.f,(4*lane+3==qk)?1.f:0.f);

    const float c=Cg[(size_t)sel*DD+lane];
    out_z[(size_t)n*DD+lane]=c;
    float df=sgt[r][lane]-c;
    float p=df*df;
    #pragma unroll
    for (int mm=32;mm;mm>>=1) p+=__shfl_xor(p,mm,64);
    if (lane==0){
      float tt=sqrtf(p);
      float dkl=-logqk;
      out_kl[n]=(tt+0.25f*tt)+dkl;
      out_dkl[n]=dkl;
    }
  };
  process(nA, wv,   ksA, trA, mA, gA0,gA1,gA2,gA3);
  process(nB, wv+8, ksB, trB, mB, gB0,gB1,gB2,gB3);
}

extern "C" void kernel_launch(void* const* d_in, const int* in_sizes, int n_in,
                              void* d_out, int out_size, void* d_ws, size_t ws_size,
                              hipStream_t stream){
  const float* z    = (const float*)d_in[1];
  const float* ksm  = (const float*)d_in[2];
  const float* xt   = (const float*)d_in[3];
  const void*  mask = d_in[4];
  const float* tr   = (const float*)d_in[5];
  const float* spk  = (const float*)d_in[6];
  const float* W1   = (const float*)d_in[7];
  const float* b1   = (const float*)d_in[8];
  const float* W2   = (const float*)d_in[9];
  const float* b2   = (const float*)d_in[10];
  const float* W3   = (const float*)d_in[11];
  const float* b3   = (const float*)d_in[12];
  const float* C    = (const float*)d_in[13];
  const int*   seed = (const int*)d_in[14];

  float* out_z   = (float*)d_out;                // N*D
  float* out_kl  = out_z   + (size_t)NN*DD;      // N
  float* out_dkl = out_kl  + NN;                 // N
  float* out_qk  = out_dkl + NN;                 // N*K

  k_fused<<<GRID,NT,0,stream>>>(z, ksm, xt, mask, tr, spk,
                                W1, b1, W2, b2, W3, b3, C, seed,
                                out_z, out_kl, out_dkl, out_qk);
}

// Round 11
// 36.966 us; speedup vs baseline: 2.0341x; 2.0341x over previous
//
#include <hip/hip_runtime.h>
#include <cstdint>
#include <cmath>

#define NN   4096
#define DXX  128
#define DD   64
#define KK   256
#define HH   256
#define DIN  192
#define ROWS 16
#define NT   512
#define GRID (NN/ROWS)   // 256 blocks, 1 per CU, 8 waves

typedef __attribute__((ext_vector_type(8))) short short8;
typedef __attribute__((ext_vector_type(4))) float f32x4;
#define MFMA __builtin_amdgcn_mfma_f32_16x16x32_bf16

// ---- packed-weight offsets in d_ws (ushort units) ----
#define OW1 0          // 3 terms x 16ct x 6ks x 512
#define OW2 147456     // 3 x 16 x 8 x 512
#define OW3 344064     // 3 x 4  x 8 x 512
#define OCT 393216     // 3 x 16 x 2 x 512
#define OCN 442368     // 256 f32 (codebook row norms)

// ---- LDS strides ----
#define SW  264        // act row stride (ushorts), 528B: 16B-aligned, 2-way-free b128
#define SG  72         // gt-split row stride (ushorts)
#define SSP 260        // score row stride (floats)
#define SSG 68         // sgt row stride (floats)

__device__ __forceinline__ unsigned short f2bf(float x){
  uint32_t u = __float_as_uint(x);
  return (unsigned short)((u + 0x7fffu + ((u>>16)&1u)) >> 16);
}
__device__ __forceinline__ float bf2f(unsigned short b){
  return __uint_as_float(((uint32_t)b)<<16);
}
__device__ __forceinline__ void split3(float x, unsigned short& h, unsigned short& m, unsigned short& l){
  h = f2bf(x); float r1 = x - bf2f(h);
  m = f2bf(r1); float r2 = r1 - bf2f(m);
  l = f2bf(r2);                       // x == bf(h)+bf(m)+bf(l) exactly (24-bit capture)
}

// ---------------- Threefry-2x32 (20 rounds), exact JAX semantics ----------------
__device__ __forceinline__ uint32_t rotl32(uint32_t v, uint32_t r){ return (v<<r)|(v>>(32u-r)); }
__device__ __forceinline__ void tf2x32(uint32_t k0, uint32_t k1,
                                       uint32_t x0, uint32_t x1,
                                       uint32_t& o0, uint32_t& o1){
  const uint32_t ks0=k0, ks1=k1, ks2 = k0 ^ k1 ^ 0x1BD11BDAu;
  x0 += ks0; x1 += ks1;
  x0+=x1; x1=rotl32(x1,13); x1^=x0;
  x0+=x1; x1=rotl32(x1,15); x1^=x0;
  x0+=x1; x1=rotl32(x1,26); x1^=x0;
  x0+=x1; x1=rotl32(x1, 6); x1^=x0;
  x0+=ks1; x1+=ks2+1u;
  x0+=x1; x1=rotl32(x1,17); x1^=x0;
  x0+=x1; x1=rotl32(x1,29); x1^=x0;
  x0+=x1; x1=rotl32(x1,16); x1^=x0;
  x0+=x1; x1=rotl32(x1,24); x1^=x0;
  x0+=ks2; x1+=ks0+2u;
  x0+=x1; x1=rotl32(x1,13); x1^=x0;
  x0+=x1; x1=rotl32(x1,15); x1^=x0;
  x0+=x1; x1=rotl32(x1,26); x1^=x0;
  x0+=x1; x1=rotl32(x1, 6); x1^=x0;
  x0+=ks0; x1+=ks1+3u;
  x0+=x1; x1=rotl32(x1,17); x1^=x0;
  x0+=x1; x1=rotl32(x1,29); x1^=x0;
  x0+=x1; x1=rotl32(x1,16); x1^=x0;
  x0+=x1; x1=rotl32(x1,24); x1^=x0;
  x0+=ks1; x1+=ks2+4u;
  x0+=x1; x1=rotl32(x1,13); x1^=x0;
  x0+=x1; x1=rotl32(x1,15); x1^=x0;
  x0+=x1; x1=rotl32(x1,26); x1^=x0;
  x0+=x1; x1=rotl32(x1, 6); x1^=x0;
  x0+=ks2; x1+=ks0+5u;
  o0=x0; o1=x1;
}
__device__ __forceinline__ float gumbel_of(uint32_t ka0, uint32_t ka1, uint32_t idx){
  uint32_t o0,o1; tf2x32(ka0,ka1,0u,idx,o0,o1);
  const uint32_t bits = o0 ^ o1;
  const float TINY = 1.17549435e-38f;
  const float f = __uint_as_float((bits>>9) | 0x3F800000u) - 1.0f;
  const float u = fmaxf(TINY, f + TINY);
  return -logf(-logf(u));
}

// ---------------- prep: split fp32 -> bf16 h/m/l, pack B-frag-friendly ----------------
__global__ __launch_bounds__(256) void k_prep(const float* __restrict__ W1,
    const float* __restrict__ W2, const float* __restrict__ W3,
    const float* __restrict__ Cg, unsigned short* __restrict__ ws){
  const int tid = blockIdx.x*256 + threadIdx.x;
  const int S1=6144, S2=8192, S3=2048, S4=2048;
  if (tid >= S1+S2+S3+S4){                    // codebook row norms
    int c = tid - (S1+S2+S3+S4);
    if (c < 256){
      float s=0.f;
      for (int d=0; d<64; ++d){ float v=Cg[(size_t)c*64+d]; s += v*v; }
      ((float*)(ws+OCN))[c] = s;
    }
    return;
  }
  const float* W; int N, KS, NTt; size_t base; int slot; bool ctm=false;
  if (tid < S1){ W=W1; N=256; KS=6; NTt=16; base=OW1; slot=tid; }
  else if (tid < S1+S2){ W=W2; N=256; KS=8; NTt=16; base=OW2; slot=tid-S1; }
  else if (tid < S1+S2+S3){ W=W3; N=64; KS=8; NTt=4; base=OW3; slot=tid-S1-S2; }
  else { W=Cg; N=64; KS=2; NTt=16; base=OCT; slot=tid-S1-S2-S3; ctm=true; }
  const int l  = slot & 63;
  const int ks = (slot>>6) % KS;
  const int ct = slot / (64*KS);
  const int c  = ct*16 + (l&15);
  const int k0 = ks*32 + 8*(l>>4);
  const size_t term = (size_t)NTt*KS*512;
  const size_t o = base + ((size_t)ct*KS + ks)*512 + (size_t)l*8;
  #pragma unroll
  for (int j=0;j<8;++j){
    float w = ctm ? W[(size_t)c*64 + (k0+j)] : W[(size_t)(k0+j)*N + c];
    unsigned short h,m,lo; split3(w,h,m,lo);
    ws[o + j]          = h;
    ws[o + term + j]   = m;
    ws[o + 2*term + j] = lo;
  }
}

// ---------------- fused main kernel ----------------
__global__ __launch_bounds__(NT,2) void k_fused(
    const float* __restrict__ z, const float* __restrict__ ks,
    const float* __restrict__ xt, const void* __restrict__ maskp,
    const float* __restrict__ tr, const float* __restrict__ spk,
    const float* __restrict__ b1, const float* __restrict__ b2,
    const float* __restrict__ b3, const float* __restrict__ Cg,
    const int* __restrict__ seedp, const unsigned short* __restrict__ pws,
    float* __restrict__ out_z, float* __restrict__ out_kl,
    float* __restrict__ out_dkl, float* __restrict__ out_qk)
{
  const int t    = threadIdx.x;
  const int lane = t & 63;
  const int wv   = t >> 6;
  const int lr   = lane & 15;         // frag row/col within 16
  const int lg   = lane >> 4;         // frag k-group
  const int n0   = blockIdx.x * ROWS;
  const int nA   = n0 + wv;
  const int nB   = n0 + 8 + wv;

  __shared__ __align__(16) char smem[61952];
  unsigned short* Ah = (unsigned short*)smem;            // bufA: layer input / h2
  unsigned short* Am = Ah + 16*SW;
  unsigned short* Al = Am + 16*SW;
  unsigned short* Bh = (unsigned short*)(smem + 25344);  // bufB: h1  (later: sp overlay)
  unsigned short* Bm = Bh + 16*SW;
  unsigned short* Bl = Bm + 16*SW;
  float* sp  = (float*)(smem + 25344);
  float* sgt = (float*)(smem + 50688);
  unsigned short* Gh = (unsigned short*)(smem + 55040);  // gt splits
  unsigned short* Gm = Gh + 16*SG;
  unsigned short* Gl = Gm + 16*SG;
  __shared__ int sh_flag;
  const float* cnormp = (const float*)(pws + OCN);

  // ---- early long-latency loads (hidden under MLP) ----
  auto kidx_of=[&](const float4& kq)->int{
    int kv=0x7fffffff;
    if (isfinite(kq.x)&&kq.x>0.5f) kv=4*lane+0;
    if (isfinite(kq.y)&&kq.y>0.5f&&4*lane+1<kv) kv=4*lane+1;
    if (isfinite(kq.z)&&kq.z>0.5f&&4*lane+2<kv) kv=4*lane+2;
    if (isfinite(kq.w)&&kq.w>0.5f&&4*lane+3<kv) kv=4*lane+3;
    unsigned long long bl=__ballot(kv!=0x7fffffff);
    if (bl){ int src=(int)__builtin_ctzll(bl); kv=__shfl(kv,src,64); } else kv=0;
    return kv;
  };
  const float4 ksA = ((const float4*)ks)[(size_t)nA*(KK/4)+lane];
  const float4 ksB = ((const float4*)ks)[(size_t)nB*(KK/4)+lane];
  const int kA = kidx_of(ksA), kB = kidx_of(ksB);
  const float4 trA = ((const float4*)tr)[(size_t)nA*(KK*KK/4)+(size_t)kA*(KK/4)+lane];
  const float4 trB = ((const float4*)tr)[(size_t)nB*(KK*KK/4)+(size_t)kB*(KK/4)+lane];
  const unsigned char mbA = ((const unsigned char*)maskp)[nA];
  const unsigned char mbB = ((const unsigned char*)maskp)[nB];
  const uint32_t      mwA = ((const uint32_t*)maskp)[nA];
  const uint32_t      mwB = ((const uint32_t*)maskp)[nB];

  if (t==0) sh_flag = 0;
  __syncthreads();
  {
    const uint32_t* mw = (const uint32_t*)maskp;
    uint32_t bad=0;
    #pragma unroll
    for (int q=0;q<2;++q){ uint32_t wd=mw[t+q*NT]; if (wd!=0u && wd!=1u && wd!=0x3F800000u) bad=1; }
    if (bad) atomicOr(&sh_flag,1);
  }

  // ---- stage layer-1 input with triple split ----
  for (int i=t; i<ROWS*DIN; i+=NT){
    int r=i/DIN, d=i%DIN; float v;
    if (d<DD){ v = z[(size_t)(n0+r)*DD+d]; if(!isfinite(v)) v=0.f; }
    else     { v = xt[(size_t)(n0+r)*DXX + (d-DD)]; }
    unsigned short h,m,l_; split3(v,h,m,l_);
    Ah[r*SW+d]=h; Am[r*SW+d]=m; Al[r*SW+d]=l_;
  }
  __syncthreads();
  const int flag = sh_flag;

  // ---- mfma GEMM layer: Y(16xN) = tanh(X(16xK) @ W + b), bf16 triple-split ----
  auto gemm_layer = [&](const unsigned short* Xh, const unsigned short* Xm, const unsigned short* Xl,
                        int KS, size_t wbase, const float* bias,
                        unsigned short* Yh, unsigned short* Ym, unsigned short* Yl){
    const int ct0 = wv*2, ct1 = ct0+1;
    const size_t term = (size_t)16*KS*512;
    const float bb0 = bias[ct0*16+lr], bb1 = bias[ct1*16+lr];
    f32x4 a00 = {bb0,bb0,bb0,bb0}, a01 = {0.f,0.f,0.f,0.f};
    f32x4 a10 = {bb1,bb1,bb1,bb1}, a11 = {0.f,0.f,0.f,0.f};
    const int ar = lr*SW + lg*8;
    #pragma unroll 2
    for (int s=0; s<KS; ++s){
      short8 ah = *(const short8*)&Xh[ar + s*32];
      short8 am = *(const short8*)&Xm[ar + s*32];
      short8 al = *(const short8*)&Xl[ar + s*32];
      const unsigned short* p0 = &pws[wbase + ((size_t)ct0*KS + s)*512 + lane*8];
      const unsigned short* p1 = &pws[wbase + ((size_t)ct1*KS + s)*512 + lane*8];
      short8 bh0 = *(const short8*)p0, bm0 = *(const short8*)(p0+term), bl0 = *(const short8*)(p0+2*term);
      short8 bh1 = *(const short8*)p1, bm1 = *(const short8*)(p1+term), bl1 = *(const short8*)(p1+2*term);
      a00=MFMA(ah,bh0,a00,0,0,0); a01=MFMA(ah,bm0,a01,0,0,0);
      a00=MFMA(am,bh0,a00,0,0,0); a01=MFMA(am,bm0,a01,0,0,0);
      a00=MFMA(al,bh0,a00,0,0,0); a01=MFMA(ah,bl0,a01,0,0,0);
      a10=MFMA(ah,bh1,a10,0,0,0); a11=MFMA(ah,bm1,a11,0,0,0);
      a10=MFMA(am,bh1,a10,0,0,0); a11=MFMA(am,bm1,a11,0,0,0);
      a10=MFMA(al,bh1,a10,0,0,0); a11=MFMA(ah,bl1,a11,0,0,0);
    }
    #pragma unroll
    for (int j=0;j<4;++j){
      const int r = lg*4 + j;
      float h0 = tanhf(a00[j]+a01[j]);
      float h1v = tanhf(a10[j]+a11[j]);
      unsigned short hh,hm,hl;
      split3(h0,hh,hm,hl);
      Yh[r*SW + ct0*16+lr]=hh; Ym[r*SW + ct0*16+lr]=hm; Yl[r*SW + ct0*16+lr]=hl;
      split3(h1v,hh,hm,hl);
      Yh[r*SW + ct1*16+lr]=hh; Ym[r*SW + ct1*16+lr]=hm; Yl[r*SW + ct1*16+lr]=hl;
    }
  };

  gemm_layer(Ah,Am,Al, 6, OW1, b1, Bh,Bm,Bl);   // h1 -> bufB
  __syncthreads();
  gemm_layer(Bh,Bm,Bl, 8, OW2, b2, Ah,Am,Al);   // h2 -> bufA
  __syncthreads();

  // ---- MLP3: gt = h2 @ W3 + b3 (waves 0-3, one 16-col tile each) ----
  if (wv < 4){
    const int ct = wv;
    const size_t term = (size_t)4*8*512;
    const float bb = b3[ct*16+lr];
    f32x4 a0 = {bb,bb,bb,bb}, a1 = {0.f,0.f,0.f,0.f};
    const int ar = lr*SW + lg*8;
    #pragma unroll 2
    for (int s=0; s<8; ++s){
      short8 ah = *(const short8*)&Ah[ar + s*32];
      short8 am = *(const short8*)&Am[ar + s*32];
      short8 al = *(const short8*)&Al[ar + s*32];
      const unsigned short* p = &pws[OW3 + ((size_t)ct*8 + s)*512 + lane*8];
      short8 bh = *(const short8*)p, bm = *(const short8*)(p+term), bl = *(const short8*)(p+2*term);
      a0=MFMA(ah,bh,a0,0,0,0); a1=MFMA(ah,bm,a1,0,0,0);
      a0=MFMA(am,bh,a0,0,0,0); a1=MFMA(am,bm,a1,0,0,0);
      a0=MFMA(al,bh,a0,0,0,0); a1=MFMA(ah,bl,a1,0,0,0);
    }
    #pragma unroll
    for (int j=0;j<4;++j){
      const int r = lg*4 + j;
      float g = a0[j]+a1[j];
      sgt[r*SSG + ct*16+lr] = g;
      unsigned short gh,gm,gl; split3(g,gh,gm,gl);
      Gh[r*SG + ct*16+lr]=gh; Gm[r*SG + ct*16+lr]=gm; Gl[r*SG + ct*16+lr]=gl;
    }
  }

  // ---- gumbel precompute (VALU, overlaps) ----
  uint32_t ka0,ka1;
  tf2x32(0u,(uint32_t)seedp[0],0u,0u,ka0,ka1);
  const bool mA = flag ? (mbA!=0) : (mwA!=0u);
  const bool mB = flag ? (mbB!=0) : (mwB!=0u);
  float gA0=0,gA1=0,gA2=0,gA3=0,gB0=0,gB1=0,gB2=0,gB3=0;
  if (!mA){
    gA0=gumbel_of(ka0,ka1,(uint32_t)(nA*KK+4*lane+0));
    gA1=gumbel_of(ka0,ka1,(uint32_t)(nA*KK+4*lane+1));
    gA2=gumbel_of(ka0,ka1,(uint32_t)(nA*KK+4*lane+2));
    gA3=gumbel_of(ka0,ka1,(uint32_t)(nA*KK+4*lane+3));
  }
  if (!mB){
    gB0=gumbel_of(ka0,ka1,(uint32_t)(nB*KK+4*lane+0));
    gB1=gumbel_of(ka0,ka1,(uint32_t)(nB*KK+4*lane+1));
    gB2=gumbel_of(ka0,ka1,(uint32_t)(nB*KK+4*lane+2));
    gB3=gumbel_of(ka0,ka1,(uint32_t)(nB*KK+4*lane+3));
  }
  __syncthreads();   // sgt/G splits ready; bufB (h1) dead -> sp overlay OK after this

  // ---- VQ scores via mfma: score[r][c] = ||C_c||^2 - 2 * (gt . C_c) ----
  {
    const int ct0 = wv*2, ct1 = ct0+1;
    const size_t term = (size_t)16*2*512;
    f32x4 s00={0.f,0.f,0.f,0.f}, s01=s00, s10=s00, s11=s00;
    const int ar = lr*SG + lg*8;
    #pragma unroll
    for (int s=0; s<2; ++s){
      short8 ah = *(const short8*)&Gh[ar + s*32];
      short8 am = *(const short8*)&Gm[ar + s*32];
      short8 al = *(const short8*)&Gl[ar + s*32];
      const unsigned short* p0 = &pws[OCT + ((size_t)ct0*2 + s)*512 + lane*8];
      const unsigned short* p1 = &pws[OCT + ((size_t)ct1*2 + s)*512 + lane*8];
      short8 bh0=*(const short8*)p0, bm0=*(const short8*)(p0+term), bl0=*(const short8*)(p0+2*term);
      short8 bh1=*(const short8*)p1, bm1=*(const short8*)(p1+term), bl1=*(const short8*)(p1+2*term);
      s00=MFMA(ah,bh0,s00,0,0,0); s01=MFMA(ah,bm0,s01,0,0,0);
      s00=MFMA(am,bh0,s00,0,0,0); s01=MFMA(am,bm0,s01,0,0,0);
      s00=MFMA(al,bh0,s00,0,0,0); s01=MFMA(ah,bl0,s01,0,0,0);
      s10=MFMA(ah,bh1,s10,0,0,0); s11=MFMA(ah,bm1,s11,0,0,0);
      s10=MFMA(am,bh1,s10,0,0,0); s11=MFMA(am,bm1,s11,0,0,0);
      s10=MFMA(al,bh1,s10,0,0,0); s11=MFMA(ah,bl1,s11,0,0,0);
    }
    const float cn0 = cnormp[ct0*16+lr], cn1 = cnormp[ct1*16+lr];
    #pragma unroll
    for (int j=0;j<4;++j){
      const int r = lg*4 + j;
      sp[r*SSP + ct0*16+lr] = cn0 - 2.f*(s00[j]+s01[j]);
      sp[r*SSP + ct1*16+lr] = cn1 - 2.f*(s10[j]+s11[j]);
    }
  }
  __syncthreads();

  // ---- wave-local finalize: wave wv owns rows nA (r=wv) and nB (r=wv+8) ----
  auto process=[&](int n,int r,const float4& ksq,const float4& trq,bool m,
                   float g0,float g1,float g2,float g3){
    const float FMX = 3.402823466e38f;
    float4 dq = *(const float4*)&sp[r*SSP + 4*lane];
    // pass 1: score argmin (first-index tie-break)
    float dv=dq.x; int di=4*lane;
    if (dq.y<dv){dv=dq.y;di=4*lane+1;}
    if (dq.z<dv){dv=dq.z;di=4*lane+2;}
    if (dq.w<dv){dv=dq.w;di=4*lane+3;}
    #pragma unroll
    for (int mm=32;mm;mm>>=1){
      float ov=__shfl_xor(dv,mm,64); int oi=__shfl_xor(di,mm,64);
      if (ov<dv||(ov==dv&&oi<di)){dv=ov;di=oi;}
    }
    const int i1=di;
    // pass 2: runner-up
    float v0=(4*lane+0==i1)?FMX:dq.x, v1=(4*lane+1==i1)?FMX:dq.y;
    float v2=(4*lane+2==i1)?FMX:dq.z, v3=(4*lane+3==i1)?FMX:dq.w;
    float ev=v0; int ei=4*lane;
    if (v1<ev){ev=v1;ei=4*lane+1;}
    if (v2<ev){ev=v2;ei=4*lane+2;}
    if (v3<ev){ev=v3;ei=4*lane+3;}
    #pragma unroll
    for (int mm=32;mm;mm>>=1){
      float ov=__shfl_xor(ev,mm,64); int oi=__shfl_xor(ei,mm,64);
      if (ov<ev||(ov==ev&&oi<ei)){ev=ov;ei=oi;}
    }
    const int i2=ei;
    // exact fp32 recheck of top-2 (ref semantics: compare sqrt'd dists, low idx ties)
    const float gd = sgt[r*SSG + lane];
    float e1 = gd - Cg[(size_t)i1*DD + lane];
    float e2 = gd - Cg[(size_t)i2*DD + lane];
    float s1 = e1*e1, s2 = e2*e2;
    #pragma unroll
    for (int mm=32;mm;mm>>=1){ s1 += __shfl_xor(s1,mm,64); s2 += __shfl_xor(s2,mm,64); }
    const float D1 = sqrtf(s1), D2 = sqrtf(s2);
    const int qk = (D2<D1 || (D2==D1 && i2<i1)) ? i2 : i1;

    // prior normalization
    float s=((trq.x+trq.y)+trq.z)+trq.w;
    #pragma unroll
    for (int mm=32;mm;mm>>=1) s+=__shfl_xor(s,mm,64);
    float q0=trq.x/s, q1=trq.y/s, q2=trq.z/s, q3=trq.w/s;
    { bool f0=isfinite(ksq.x),f1=isfinite(ksq.y),f2=isfinite(ksq.z),f3=isfinite(ksq.w);
      if (__any(!(f0&&f1&&f2&&f3))){
        float4 sq=((const float4*)spk)[(size_t)n*(KK/4)+lane];
        if(!f0)q0=sq.x; if(!f1)q1=sq.y; if(!f2)q2=sq.z; if(!f3)q3=sq.w;
      } }
    const float lp0=logf(q0), lp1=logf(q1), lp2=logf(q2), lp3=logf(q3);
    const int jq=qk&3;
    float lps=(jq==0)?lp0:((jq==1)?lp1:((jq==2)?lp2:lp3));
    const float logqk=__shfl(lps,qk>>2,64);

    int sel;
    if (m){ sel=qk; }
    else {
      float sc=g0+lp0; int si=4*lane;
      { float g=g1+lp1; if(g>sc){sc=g;si=4*lane+1;} }
      { float g=g2+lp2; if(g>sc){sc=g;si=4*lane+2;} }
      { float g=g3+lp3; if(g>sc){sc=g;si=4*lane+3;} }
      #pragma unroll
      for (int mm=32;mm;mm>>=1){
        float ov=__shfl_xor(sc,mm,64); int oi=__shfl_xor(si,mm,64);
        if (ov>sc||(ov==sc&&oi<si)){sc=ov;si=oi;}
      }
      sel=si;
    }

    ((float4*)out_qk)[(size_t)n*(KK/4)+lane]=make_float4(
      (4*lane+0==qk)?1.f:0.f,(4*lane+1==qk)?1.f:0.f,
      (4*lane+2==qk)?1.f:0.f,(4*lane+3==qk)?1.f:0.f);

    const float c=Cg[(size_t)sel*DD+lane];
    out_z[(size_t)n*DD+lane]=c;
    float df = sgt[r*SSG + lane] - c;
    float p=df*df;
    #pragma unroll
    for (int mm=32;mm;mm>>=1) p+=__shfl_xor(p,mm,64);
    if (lane==0){
      float tt=sqrtf(p);
      float dkl=-logqk;
      out_kl[n]=(tt+0.25f*tt)+dkl;
      out_dkl[n]=dkl;
    }
  };
  process(nA, wv,   ksA, trA, mA, gA0,gA1,gA2,gA3);
  process(nB, wv+8, ksB, trB, mB, gB0,gB1,gB2,gB3);
}

extern "C" void kernel_launch(void* const* d_in, const int* in_sizes, int n_in,
                              void* d_out, int out_size, void* d_ws, size_t ws_size,
                              hipStream_t stream){
  const float* z    = (const float*)d_in[1];
  const float* ksm  = (const float*)d_in[2];
  const float* xt   = (const float*)d_in[3];
  const void*  mask = d_in[4];
  const float* tr   = (const float*)d_in[5];
  const float* spk  = (const float*)d_in[6];
  const float* W1   = (const float*)d_in[7];
  const float* b1   = (const float*)d_in[8];
  const float* W2   = (const float*)d_in[9];
  const float* b2   = (const float*)d_in[10];
  const float* W3   = (const float*)d_in[11];
  const float* b3   = (const float*)d_in[12];
  const float* C    = (const float*)d_in[13];
  const int*   seed = (const int*)d_in[14];

  float* out_z   = (float*)d_out;                // N*D
  float* out_kl  = out_z   + (size_t)NN*DD;      // N
  float* out_dkl = out_kl  + NN;                 // N
  float* out_qk  = out_dkl + NN;                 // N*K

  unsigned short* ws = (unsigned short*)d_ws;
  k_prep<<<73,256,0,stream>>>(W1, W2, W3, C, ws);
  k_fused<<<GRID,NT,0,stream>>>(z, ksm, xt, mask, tr, spk,
                                b1, b2, b3, C, seed, ws,
                                out_z, out_kl, out_dkl, out_qk);
}

// Round 12
// 30.992 us; speedup vs baseline: 2.4261x; 1.1927x over previous
//
#include <hip/hip_runtime.h>
#include <cstdint>
#include <cmath>

#define NN   4096
#define DXX  128
#define DD   64
#define KK   256
#define HH   256
#define DIN  192
#define ROWS 16
#define NT   1024
#define GRID (NN/ROWS)   // 256 blocks, 1 per CU, 16 waves -> 4 waves/SIMD

typedef __attribute__((ext_vector_type(8))) short short8;
typedef __attribute__((ext_vector_type(4))) float f32x4;
#define MFMA __builtin_amdgcn_mfma_f32_16x16x32_bf16

// ---- packed-weight offsets in d_ws (ushort units) ----
#define OW1 0          // 3 terms x 16ct x 6ks x 512
#define OW2 147456     // 3 x 16 x 8 x 512
#define OW3 344064     // 3 x 4  x 8 x 512
#define OCT 393216     // 3 x 16 x 2 x 512
#define OCN 442368     // 256 f32 (codebook row norms)

// ---- LDS strides ----
#define SW  264        // act row stride (ushorts)
#define SG  72         // gt-split row stride (ushorts)
#define SSP 260        // score row stride (floats)
#define SSG 68         // sgt row stride (floats)

__device__ __forceinline__ unsigned short f2bf(float x){
  uint32_t u = __float_as_uint(x);
  return (unsigned short)((u + 0x7fffu + ((u>>16)&1u)) >> 16);
}
__device__ __forceinline__ float bf2f(unsigned short b){
  return __uint_as_float(((uint32_t)b)<<16);
}
__device__ __forceinline__ void split3(float x, unsigned short& h, unsigned short& m, unsigned short& l){
  h = f2bf(x); float r1 = x - bf2f(h);
  m = f2bf(r1); float r2 = r1 - bf2f(m);
  l = f2bf(r2);
}

// ---------------- Threefry-2x32 (20 rounds), exact JAX semantics ----------------
__device__ __forceinline__ uint32_t rotl32(uint32_t v, uint32_t r){ return (v<<r)|(v>>(32u-r)); }
__device__ __forceinline__ void tf2x32(uint32_t k0, uint32_t k1,
                                       uint32_t x0, uint32_t x1,
                                       uint32_t& o0, uint32_t& o1){
  const uint32_t ks0=k0, ks1=k1, ks2 = k0 ^ k1 ^ 0x1BD11BDAu;
  x0 += ks0; x1 += ks1;
  x0+=x1; x1=rotl32(x1,13); x1^=x0;
  x0+=x1; x1=rotl32(x1,15); x1^=x0;
  x0+=x1; x1=rotl32(x1,26); x1^=x0;
  x0+=x1; x1=rotl32(x1, 6); x1^=x0;
  x0+=ks1; x1+=ks2+1u;
  x0+=x1; x1=rotl32(x1,17); x1^=x0;
  x0+=x1; x1=rotl32(x1,29); x1^=x0;
  x0+=x1; x1=rotl32(x1,16); x1^=x0;
  x0+=x1; x1=rotl32(x1,24); x1^=x0;
  x0+=ks2; x1+=ks0+2u;
  x0+=x1; x1=rotl32(x1,13); x1^=x0;
  x0+=x1; x1=rotl32(x1,15); x1^=x0;
  x0+=x1; x1=rotl32(x1,26); x1^=x0;
  x0+=x1; x1=rotl32(x1, 6); x1^=x0;
  x0+=ks0; x1+=ks1+3u;
  x0+=x1; x1=rotl32(x1,17); x1^=x0;
  x0+=x1; x1=rotl32(x1,29); x1^=x0;
  x0+=x1; x1=rotl32(x1,16); x1^=x0;
  x0+=x1; x1=rotl32(x1,24); x1^=x0;
  x0+=ks1; x1+=ks2+4u;
  x0+=x1; x1=rotl32(x1,13); x1^=x0;
  x0+=x1; x1=rotl32(x1,15); x1^=x0;
  x0+=x1; x1=rotl32(x1,26); x1^=x0;
  x0+=x1; x1=rotl32(x1, 6); x1^=x0;
  x0+=ks2; x1+=ks0+5u;
  o0=x0; o1=x1;
}
__device__ __forceinline__ float gumbel_of(uint32_t ka0, uint32_t ka1, uint32_t idx){
  uint32_t o0,o1; tf2x32(ka0,ka1,0u,idx,o0,o1);
  const uint32_t bits = o0 ^ o1;
  const float TINY = 1.17549435e-38f;
  const float f = __uint_as_float((bits>>9) | 0x3F800000u) - 1.0f;
  const float u = fmaxf(TINY, f + TINY);
  return -logf(-logf(u));
}

// ---------------- prep: split fp32 -> bf16 h/m/l, pack B-frag-friendly ----------------
__global__ __launch_bounds__(256) void k_prep(const float* __restrict__ W1,
    const float* __restrict__ W2, const float* __restrict__ W3,
    const float* __restrict__ Cg, unsigned short* __restrict__ ws){
  const int tid = blockIdx.x*256 + threadIdx.x;
  const int S1=6144, S2=8192, S3=2048, S4=2048;
  if (tid >= S1+S2+S3+S4){
    int c = tid - (S1+S2+S3+S4);
    if (c < 256){
      float s=0.f;
      for (int d=0; d<64; ++d){ float v=Cg[(size_t)c*64+d]; s += v*v; }
      ((float*)(ws+OCN))[c] = s;
    }
    return;
  }
  const float* W; int N, KS, NTt; size_t base; int slot; bool ctm=false;
  if (tid < S1){ W=W1; N=256; KS=6; NTt=16; base=OW1; slot=tid; }
  else if (tid < S1+S2){ W=W2; N=256; KS=8; NTt=16; base=OW2; slot=tid-S1; }
  else if (tid < S1+S2+S3){ W=W3; N=64; KS=8; NTt=4; base=OW3; slot=tid-S1-S2; }
  else { W=Cg; N=64; KS=2; NTt=16; base=OCT; slot=tid-S1-S2-S3; ctm=true; }
  const int l  = slot & 63;
  const int ks = (slot>>6) % KS;
  const int ct = slot / (64*KS);
  const int c  = ct*16 + (l&15);
  const int k0 = ks*32 + 8*(l>>4);
  const size_t term = (size_t)NTt*KS*512;
  const size_t o = base + ((size_t)ct*KS + ks)*512 + (size_t)l*8;
  #pragma unroll
  for (int j=0;j<8;++j){
    float w = ctm ? W[(size_t)c*64 + (k0+j)] : W[(size_t)(k0+j)*N + c];
    unsigned short h,m,lo; split3(w,h,m,lo);
    ws[o + j]          = h;
    ws[o + term + j]   = m;
    ws[o + 2*term + j] = lo;
  }
}

// ---------------- fused main kernel: 16 waves, 1 ct/wave ----------------
__global__ __launch_bounds__(NT,4) void k_fused(
    const float* __restrict__ z, const float* __restrict__ ks,
    const float* __restrict__ xt, const void* __restrict__ maskp,
    const float* __restrict__ tr, const float* __restrict__ spk,
    const float* __restrict__ b1, const float* __restrict__ b2,
    const float* __restrict__ b3, const float* __restrict__ Cg,
    const int* __restrict__ seedp, const unsigned short* __restrict__ pws,
    float* __restrict__ out_z, float* __restrict__ out_kl,
    float* __restrict__ out_dkl, float* __restrict__ out_qk)
{
  const int t    = threadIdx.x;
  const int lane = t & 63;
  const int wv   = t >> 6;            // wave 0..15
  const int lr   = lane & 15;
  const int lg   = lane >> 4;
  const int n0   = blockIdx.x * ROWS;
  const int nw   = n0 + wv;           // finalize: wave wv owns row nw

  __shared__ __align__(16) char smem[61952];
  unsigned short* Ah = (unsigned short*)smem;            // bufA: layer input / h2
  unsigned short* Am = Ah + 16*SW;
  unsigned short* Al = Am + 16*SW;
  unsigned short* Bh = (unsigned short*)(smem + 25344);  // bufB: h1 (later sp overlay)
  unsigned short* Bm = Bh + 16*SW;
  unsigned short* Bl = Bm + 16*SW;
  float* sp  = (float*)(smem + 25344);
  float* sgt = (float*)(smem + 50688);
  unsigned short* Gh = (unsigned short*)(smem + 55040);
  unsigned short* Gm = Gh + 16*SG;
  unsigned short* Gl = Gm + 16*SG;
  __shared__ int sh_flag;
  const float* cnormp = (const float*)(pws + OCN);

  // ---- early long-latency loads (hidden under MLP) ----
  const float4 ksq = ((const float4*)ks)[(size_t)nw*(KK/4)+lane];
  int kv=0x7fffffff;
  if (isfinite(ksq.x)&&ksq.x>0.5f) kv=4*lane+0;
  if (isfinite(ksq.y)&&ksq.y>0.5f&&4*lane+1<kv) kv=4*lane+1;
  if (isfinite(ksq.z)&&ksq.z>0.5f&&4*lane+2<kv) kv=4*lane+2;
  if (isfinite(ksq.w)&&ksq.w>0.5f&&4*lane+3<kv) kv=4*lane+3;
  { unsigned long long bl=__ballot(kv!=0x7fffffff);
    if (bl){ int src=(int)__builtin_ctzll(bl); kv=__shfl(kv,src,64); } else kv=0; }
  const int kidx = kv;
  const float4 trq = ((const float4*)tr)[(size_t)nw*(KK*KK/4)+(size_t)kidx*(KK/4)+lane];
  const unsigned char mb = ((const unsigned char*)maskp)[nw];
  const uint32_t      mw32 = ((const uint32_t*)maskp)[nw];

  if (t==0) sh_flag = 0;
  __syncthreads();
  {
    const uint32_t* mwp = (const uint32_t*)maskp;
    uint32_t wd = mwp[t];            // words 0..1023 (= full byte-mask / first 1024 rows)
    if (wd!=0u && wd!=1u && wd!=0x3F800000u) atomicOr(&sh_flag,1);
  }

  // ---- stage layer-1 input with triple split ----
  for (int i=t; i<ROWS*DIN; i+=NT){
    int r=i/DIN, d=i%DIN; float v;
    if (d<DD){ v = z[(size_t)(n0+r)*DD+d]; if(!isfinite(v)) v=0.f; }
    else     { v = xt[(size_t)(n0+r)*DXX + (d-DD)]; }
    unsigned short h,m,l_; split3(v,h,m,l_);
    Ah[r*SW+d]=h; Am[r*SW+d]=m; Al[r*SW+d]=l_;
  }
  __syncthreads();
  const int flag = sh_flag;

  // ---- mfma GEMM layer (1 ct per wave), depth-1 weight prefetch ----
  auto gemm_layer = [&](const unsigned short* Xh, const unsigned short* Xm, const unsigned short* Xl,
                        int KS, size_t wbase, const float* bias,
                        unsigned short* Yh, unsigned short* Ym, unsigned short* Yl){
    const int ct = wv;
    const size_t term = (size_t)16*KS*512;
    const float bb = bias[ct*16+lr];
    f32x4 a0 = {bb,bb,bb,bb}, a1 = {0.f,0.f,0.f,0.f};
    const int ar = lr*SW + lg*8;
    const unsigned short* p = &pws[wbase + ((size_t)ct*KS)*512 + (size_t)lane*8];
    short8 bh = *(const short8*)p, bm = *(const short8*)(p+term), bl = *(const short8*)(p+2*term);
    #pragma unroll 1
    for (int s=0; s<KS; ++s){
      short8 nbh, nbm, nbl;
      if (s+1<KS){
        const unsigned short* q = p + (size_t)(s+1)*512;
        nbh=*(const short8*)q; nbm=*(const short8*)(q+term); nbl=*(const short8*)(q+2*term);
      }
      short8 ah = *(const short8*)&Xh[ar + s*32];
      short8 am = *(const short8*)&Xm[ar + s*32];
      short8 al = *(const short8*)&Xl[ar + s*32];
      a0=MFMA(ah,bh,a0,0,0,0); a1=MFMA(ah,bm,a1,0,0,0);
      a0=MFMA(am,bh,a0,0,0,0); a1=MFMA(am,bm,a1,0,0,0);
      a0=MFMA(al,bh,a0,0,0,0); a1=MFMA(ah,bl,a1,0,0,0);
      bh=nbh; bm=nbm; bl=nbl;
    }
    #pragma unroll
    for (int j=0;j<4;++j){
      const int r = lg*4 + j;
      float h0 = tanhf(a0[j]+a1[j]);
      unsigned short hh,hm,hl; split3(h0,hh,hm,hl);
      Yh[r*SW + ct*16+lr]=hh; Ym[r*SW + ct*16+lr]=hm; Yl[r*SW + ct*16+lr]=hl;
    }
  };

  gemm_layer(Ah,Am,Al, 6, OW1, b1, Bh,Bm,Bl);   // h1 -> bufB
  __syncthreads();
  gemm_layer(Bh,Bm,Bl, 8, OW2, b2, Ah,Am,Al);   // h2 -> bufA
  __syncthreads();

  // ---- MLP3: gt = h2 @ W3 + b3 (waves 0-3, one 16-col tile each) ----
  if (wv < 4){
    const int ct = wv;
    const size_t term = (size_t)4*8*512;
    const float bb = b3[ct*16+lr];
    f32x4 a0 = {bb,bb,bb,bb}, a1 = {0.f,0.f,0.f,0.f};
    const int ar = lr*SW + lg*8;
    const unsigned short* p = &pws[OW3 + ((size_t)ct*8)*512 + (size_t)lane*8];
    short8 bh = *(const short8*)p, bm = *(const short8*)(p+term), bl = *(const short8*)(p+2*term);
    #pragma unroll 1
    for (int s=0; s<8; ++s){
      short8 nbh, nbm, nbl;
      if (s+1<8){
        const unsigned short* q = p + (size_t)(s+1)*512;
        nbh=*(const short8*)q; nbm=*(const short8*)(q+term); nbl=*(const short8*)(q+2*term);
      }
      short8 ah = *(const short8*)&Ah[ar + s*32];
      short8 am = *(const short8*)&Am[ar + s*32];
      short8 al = *(const short8*)&Al[ar + s*32];
      a0=MFMA(ah,bh,a0,0,0,0); a1=MFMA(ah,bm,a1,0,0,0);
      a0=MFMA(am,bh,a0,0,0,0); a1=MFMA(am,bm,a1,0,0,0);
      a0=MFMA(al,bh,a0,0,0,0); a1=MFMA(ah,bl,a1,0,0,0);
      bh=nbh; bm=nbm; bl=nbl;
    }
    #pragma unroll
    for (int j=0;j<4;++j){
      const int r = lg*4 + j;
      float g = a0[j]+a1[j];
      sgt[r*SSG + ct*16+lr] = g;
      unsigned short gh,gm,gl; split3(g,gh,gm,gl);
      Gh[r*SG + ct*16+lr]=gh; Gm[r*SG + ct*16+lr]=gm; Gl[r*SG + ct*16+lr]=gl;
    }
  }

  // ---- gumbel precompute (VALU, overlaps L3) ----
  uint32_t ka0,ka1;
  tf2x32(0u,(uint32_t)seedp[0],0u,0u,ka0,ka1);
  const bool m = flag ? (mb!=0) : (mw32!=0u);
  float g0=0,g1=0,g2=0,g3=0;
  if (!m){
    g0=gumbel_of(ka0,ka1,(uint32_t)(nw*KK+4*lane+0));
    g1=gumbel_of(ka0,ka1,(uint32_t)(nw*KK+4*lane+1));
    g2=gumbel_of(ka0,ka1,(uint32_t)(nw*KK+4*lane+2));
    g3=gumbel_of(ka0,ka1,(uint32_t)(nw*KK+4*lane+3));
  }
  __syncthreads();   // sgt/G ready; bufB (h1) dead -> sp overlay OK

  // ---- VQ scores via mfma: score[r][c] = ||C_c||^2 - 2 * (gt . C_c) ----
  {
    const int ct = wv;
    const size_t term = (size_t)16*2*512;
    f32x4 s0={0.f,0.f,0.f,0.f}, s1=s0;
    const int ar = lr*SG + lg*8;
    #pragma unroll
    for (int s=0; s<2; ++s){
      short8 ah = *(const short8*)&Gh[ar + s*32];
      short8 am = *(const short8*)&Gm[ar + s*32];
      short8 al = *(const short8*)&Gl[ar + s*32];
      const unsigned short* p = &pws[OCT + ((size_t)ct*2 + s)*512 + (size_t)lane*8];
      short8 bh=*(const short8*)p, bm=*(const short8*)(p+term), bl=*(const short8*)(p+2*term);
      s0=MFMA(ah,bh,s0,0,0,0); s1=MFMA(ah,bm,s1,0,0,0);
      s0=MFMA(am,bh,s0,0,0,0); s1=MFMA(am,bm,s1,0,0,0);
      s0=MFMA(al,bh,s0,0,0,0); s1=MFMA(ah,bl,s1,0,0,0);
    }
    const float cn = cnormp[ct*16+lr];
    #pragma unroll
    for (int j=0;j<4;++j){
      const int r = lg*4 + j;
      sp[r*SSP + ct*16+lr] = cn - 2.f*(s0[j]+s1[j]);
    }
  }
  __syncthreads();

  // ---- wave-local finalize: wave wv owns row nw ----
  {
    const int n = nw, r = wv;
    const float FMX = 3.402823466e38f;
    float4 dq = *(const float4*)&sp[r*SSP + 4*lane];
    float dv=dq.x; int di=4*lane;
    if (dq.y<dv){dv=dq.y;di=4*lane+1;}
    if (dq.z<dv){dv=dq.z;di=4*lane+2;}
    if (dq.w<dv){dv=dq.w;di=4*lane+3;}
    #pragma unroll
    for (int mm=32;mm;mm>>=1){
      float ov=__shfl_xor(dv,mm,64); int oi=__shfl_xor(di,mm,64);
      if (ov<dv||(ov==dv&&oi<di)){dv=ov;di=oi;}
    }
    const int i1=di;
    float v0=(4*lane+0==i1)?FMX:dq.x, v1=(4*lane+1==i1)?FMX:dq.y;
    float v2=(4*lane+2==i1)?FMX:dq.z, v3=(4*lane+3==i1)?FMX:dq.w;
    float ev=v0; int ei=4*lane;
    if (v1<ev){ev=v1;ei=4*lane+1;}
    if (v2<ev){ev=v2;ei=4*lane+2;}
    if (v3<ev){ev=v3;ei=4*lane+3;}
    #pragma unroll
    for (int mm=32;mm;mm>>=1){
      float ov=__shfl_xor(ev,mm,64); int oi=__shfl_xor(ei,mm,64);
      if (ov<ev||(ov==ev&&oi<ei)){ev=ov;ei=oi;}
    }
    const int i2=ei;
    // exact fp32 recheck of top-2
    const float gd = sgt[r*SSG + lane];
    float e1 = gd - Cg[(size_t)i1*DD + lane];
    float e2 = gd - Cg[(size_t)i2*DD + lane];
    float s1 = e1*e1, s2 = e2*e2;
    #pragma unroll
    for (int mm=32;mm;mm>>=1){ s1 += __shfl_xor(s1,mm,64); s2 += __shfl_xor(s2,mm,64); }
    const float D1 = sqrtf(s1), D2 = sqrtf(s2);
    const int qk = (D2<D1 || (D2==D1 && i2<i1)) ? i2 : i1;

    // prior normalization
    float s=((trq.x+trq.y)+trq.z)+trq.w;
    #pragma unroll
    for (int mm=32;mm;mm>>=1) s+=__shfl_xor(s,mm,64);
    float q0=trq.x/s, q1=trq.y/s, q2=trq.z/s, q3=trq.w/s;
    { bool f0=isfinite(ksq.x),f1=isfinite(ksq.y),f2=isfinite(ksq.z),f3=isfinite(ksq.w);
      if (__any(!(f0&&f1&&f2&&f3))){
        float4 sq=((const float4*)spk)[(size_t)n*(KK/4)+lane];
        if(!f0)q0=sq.x; if(!f1)q1=sq.y; if(!f2)q2=sq.z; if(!f3)q3=sq.w;
      } }
    const float lp0=logf(q0), lp1=logf(q1), lp2=logf(q2), lp3=logf(q3);
    const int jq=qk&3;
    float lps=(jq==0)?lp0:((jq==1)?lp1:((jq==2)?lp2:lp3));
    const float logqk=__shfl(lps,qk>>2,64);

    int sel;
    if (m){ sel=qk; }
    else {
      float sc=g0+lp0; int si=4*lane;
      { float g=g1+lp1; if(g>sc){sc=g;si=4*lane+1;} }
      { float g=g2+lp2; if(g>sc){sc=g;si=4*lane+2;} }
      { float g=g3+lp3; if(g>sc){sc=g;si=4*lane+3;} }
      #pragma unroll
      for (int mm=32;mm;mm>>=1){
        float ov=__shfl_xor(sc,mm,64); int oi=__shfl_xor(si,mm,64);
        if (ov>sc||(ov==sc&&oi<si)){sc=ov;si=oi;}
      }
      sel=si;
    }

    ((float4*)out_qk)[(size_t)n*(KK/4)+lane]=make_float4(
      (4*lane+0==qk)?1.f:0.f,(4*lane+1==qk)?1.f:0.f,
      (4*lane+2==qk)?1.f:0.f,(4*lane+3==qk)?1.f:0.f);

    const float c=Cg[(size_t)sel*DD+lane];
    out_z[(size_t)n*DD+lane]=c;
    float df = sgt[r*SSG + lane] - c;
    float p=df*df;
    #pragma unroll
    for (int mm=32;mm;mm>>=1) p+=__shfl_xor(p,mm,64);
    if (lane==0){
      float tt=sqrtf(p);
      float dkl=-logqk;
      out_kl[n]=(tt+0.25f*tt)+dkl;
      out_dkl[n]=dkl;
    }
  }
}

extern "C" void kernel_launch(void* const* d_in, const int* in_sizes, int n_in,
                              void* d_out, int out_size, void* d_ws, size_t ws_size,
                              hipStream_t stream){
  const float* z    = (const float*)d_in[1];
  const float* ksm  = (const float*)d_in[2];
  const float* xt   = (const float*)d_in[3];
  const void*  mask = d_in[4];
  const float* tr   = (const float*)d_in[5];
  const float* spk  = (const float*)d_in[6];
  const float* W1   = (const float*)d_in[7];
  const float* b1   = (const float*)d_in[8];
  const float* W2   = (const float*)d_in[9];
  const float* b2   = (const float*)d_in[10];
  const float* W3   = (const float*)d_in[11];
  const float* b3   = (const float*)d_in[12];
  const float* C    = (const float*)d_in[13];
  const int*   seed = (const int*)d_in[14];

  float* out_z   = (float*)d_out;                // N*D
  float* out_kl  = out_z   + (size_t)NN*DD;      // N
  float* out_dkl = out_kl  + NN;                 // N
  float* out_qk  = out_dkl + NN;                 // N*K

  unsigned short* ws = (unsigned short*)d_ws;
  k_prep<<<73,256,0,stream>>>(W1, W2, W3, C, ws);
  k_fused<<<GRID,NT,0,stream>>>(z, ksm, xt, mask, tr, spk,
                                b1, b2, b3, C, seed, ws,
                                out_z, out_kl, out_dkl, out_qk);
}